// Round 3
// baseline (2582.851 us; speedup 1.0000x reference)
//
#include <hip/hip_runtime.h>
#include <hip/hip_bf16.h>
#include <math.h>

#define NTHREADS 256
#define BSZ 128
#define TSTEPS 32
#define DIN 128
#define DHH 128
#define NSLOT 512
#define EPSF 1e-8f

static constexpr int SMEM_FLOATS = 6072;

// ---------- bf16 <-> f32 via native conversions ----------
__device__ __forceinline__ float us2f(unsigned short u) {
  union { unsigned short s; __hip_bfloat16 h; } c; c.s = u; return __bfloat162float(c.h);
}
__device__ __forceinline__ unsigned short f2us(float f) {
  union { unsigned short s; __hip_bfloat16 h; } c; c.h = __float2bfloat16(f); return c.s;
}

// Generic input load / output store: F32=true reads/writes float32 containers.
template <bool F32> __device__ __forceinline__ float LD(const void* p, int i) {
  if constexpr (F32) return ((const float*)p)[i];
  else return __bfloat162float(((const __hip_bfloat16*)p)[i]);
}
template <bool F32> __device__ __forceinline__ void ST(void* p, size_t i, float v) {
  if constexpr (F32) ((float*)p)[i] = v;
  else ((__hip_bfloat16*)p)[i] = __float2bfloat16(v);
}

// Decide input container format from raw bits of a weight buffer.
// f32 storage <=> (all low16 zero: bf16-valued-in-f32) OR (some half decodes
// to bf16 NaN/Inf: impossible for genuine packed-bf16 normal weights).
__device__ __forceinline__ bool sniff_f32(const void* w) {
  const unsigned* u = (const unsigned*)w;
  bool low_all_zero = true, bf16_bad = false;
  for (int i = 0; i < 2048; ++i) {
    unsigned v = u[i];
    if (v & 0xffffu) low_all_zero = false;
    if (((v >> 7) & 0xffu) == 0xffu || ((v >> 23) & 0xffu) == 0xffu) bf16_bad = true;
  }
  return low_all_zero || bf16_bad;
}

__device__ __forceinline__ float sigmoid_(float x) { return 1.0f / (1.0f + expf(-x)); }
__device__ __forceinline__ float softplus_(float x) {
  return fmaxf(x, 0.0f) + log1pf(expf(-fabsf(x)));
}
__device__ __forceinline__ float tanh_(float x) {
  float e = expf(-2.0f * fabsf(x));
  float t = (1.0f - e) / (1.0f + e);
  return copysignf(t, x);
}
__device__ __forceinline__ float waveSum(float v) {
#pragma unroll
  for (int m = 32; m >= 1; m >>= 1) v += __shfl_xor(v, m);
  return v;
}
__device__ __forceinline__ float waveMax(float v) {
#pragma unroll
  for (int m = 32; m >= 1; m >>= 1) v = fmaxf(v, __shfl_xor(v, m));
  return v;
}

#define CHK(v, bit) do { if (!(fabsf(v) < 1e30f)) atomicOr(sBadU, 1u << (bit)); } while (0)

// One NTM attention head over 512 slots; thread owns slots tid and tid+256.
__device__ __forceinline__ void attention_phase(
    int tid, const float* __restrict__ dot, const float* __restrict__ nrm,
    float beta, float g, float s0, float s1, float s2, float gam, float kn,
    const float* __restrict__ wprev, float* __restrict__ wg,
    float* __restrict__ wout_, float* __restrict__ sP)
{
  const int n0 = tid, n1 = tid + 256;
  const int lane = tid & 63, wid = tid >> 6;

  const float sc0 = beta * dot[n0] / (nrm[n0] * kn + EPSF);
  const float sc1 = beta * dot[n1] / (nrm[n1] * kn + EPSF);
  float mx = waveMax(fmaxf(sc0, sc1));
  if (lane == 0) sP[wid] = mx;
  __syncthreads();
  const float M = fmaxf(fmaxf(sP[0], sP[1]), fmaxf(sP[2], sP[3]));
  const float e0 = __expf(sc0 - M);
  const float e1 = __expf(sc1 - M);
  float S = waveSum(e0 + e1);
  if (lane == 0) sP[4 + wid] = S;
  __syncthreads();
  const float inv = 1.0f / (sP[4] + sP[5] + sP[6] + sP[7]);
  wg[n0] = g * (e0 * inv) + (1.0f - g) * wprev[n0];
  wg[n1] = g * (e1 * inv) + (1.0f - g) * wprev[n1];
  __syncthreads();
  const float wt0 = s0 * wg[(n0 + 1) & 511] + s1 * wg[n0] + s2 * wg[(n0 - 1) & 511];
  const float wt1 = s0 * wg[(n1 + 1) & 511] + s1 * wg[n1] + s2 * wg[(n1 - 1) & 511];
  const float p0 = powf(fmaxf(wt0, 0.0f), gam);
  const float p1 = powf(fmaxf(wt1, 0.0f), gam);
  float P = waveSum(p0 + p1);
  if (lane == 0) sP[8 + wid] = P;
  __syncthreads();
  const float pinv = 1.0f / (sP[8] + sP[9] + sP[10] + sP[11] + EPSF);
  wout_[n0] = p0 * pinv;
  wout_[n1] = p1 * pinv;
  __syncthreads();
}

// One block per batch element. Self-gates on the sniffed input format so that
// exactly one of the two template instantiations runs.
template <bool F32>
__global__ __launch_bounds__(NTHREADS, 1)
void ntm_kernel(const void* __restrict__ x,
                const void* __restrict__ Wxh,
                const void* __restrict__ Whh,
                const void* __restrict__ Wrh,
                const void* __restrict__ bh,
                const void* __restrict__ Wout,
                const void* __restrict__ bout,
                const void* __restrict__ Wr,
                const void* __restrict__ br,
                const void* __restrict__ Ww,
                const void* __restrict__ bw,
                unsigned short* __restrict__ memg,
                void* __restrict__ out)
{
  if (sniff_f32(Wxh) != F32) return;    // uniform exit, before any barrier

  extern __shared__ char smem[];
  const int b = blockIdx.x;
  const int tid = threadIdx.x;
  const int g = tid >> 4, l = tid & 15;
  const int lane = tid & 63, wid = tid >> 6;

  float* F = (float*)smem;
  uint4* memv = (uint4*)(memg + (size_t)b * NSLOT * DHH);  // bf16 mem state

  float* sWprev = F + 0;      // 512
  float* sWr    = F + 512;    // 512
  float* sWg    = F + 1024;   // 512
  float* sDotR  = F + 1536;   // 512
  float* sDotW  = F + 2048;   // 512
  float* sNrm   = F + 2560;   // 512
  float* sRed   = F + 3072;   // 2048
  float* sOr    = F + 5120;   // 144 (134 used)
  float* sOw    = F + 5264;   // 392 (390 used)
  float* sH     = F + 5656;   // 128
  float* sR     = F + 5784;   // 128
  float* sXt    = F + 5912;   // 128
  float* sP     = F + 6040;   // 32: [0..3] knorm, [4..15] attn1, [16..27] attn2
  unsigned* sBadU = (unsigned*)&sP[31];

  // ---- init (every launch; d_ws re-poisoned by harness) ----
  {
    const unsigned short mb = f2us(1e-6f);
    const unsigned w32 = ((unsigned)mb << 16) | mb;
    const uint4 fv = make_uint4(w32, w32, w32, w32);
    for (int i = tid; i < NSLOT * DHH / 8; i += NTHREADS) memv[i] = fv;
  }
  for (int i = tid; i < NSLOT; i += NTHREADS) sWprev[i] = 1.0f / NSLOT;
  if (tid < DHH) { sH[tid] = 0.0f; sR[tid] = 0.0f; }
  if (tid == 0) *sBadU = 0u;
  __syncthreads();

  // ---- phase-0 probe: scan all inputs for NaN/Inf under the chosen decode ----
  {
    const struct { const void* p; int n; } bufs[10] = {
      {Wxh, DIN * DHH}, {Whh, DHH * DHH}, {Wrh, DHH * DHH}, {bh, DHH},
      {Wout, 2 * DHH * DIN}, {bout, DIN}, {Wr, DHH * 134}, {br, 134},
      {Ww, DHH * 390}, {bw, 390}
    };
    for (int k = 0; k < 10; ++k)
      for (int i = tid; i < bufs[k].n; i += NTHREADS) {
        float v = LD<F32>(bufs[k].p, i);
        CHK(v, 0);
      }
    for (int i = tid; i < TSTEPS * DIN; i += NTHREADS) {
      float v = LD<F32>(x, b * TSTEPS * DIN + i);
      CHK(v, 0);
    }
  }
  __syncthreads();

  for (int t = 0; t < TSTEPS; ++t) {
    if (tid < DIN) {
      sXt[tid] = LD<F32>(x, (b * TSTEPS + t) * DIN + tid);
      CHK(sXt[tid], 1);
    }
    __syncthreads();

    // ---- Phase H ----
    {
      const int j = tid & 127, p = tid >> 7;
      const int i0 = p * 64;
      float acc = 0.0f;
#pragma unroll 8
      for (int i = i0; i < i0 + 64; ++i) {
        acc += sXt[i] * LD<F32>(Wxh, i * DHH + j);
        acc += sH[i]  * LD<F32>(Whh, i * DHH + j);
        acc += sR[i]  * LD<F32>(Wrh, i * DHH + j);
      }
      sRed[tid] = acc;
      __syncthreads();
      if (tid < DHH) {
        sH[tid] = tanh_(sRed[tid] + sRed[tid + 128] + LD<F32>(bh, tid));
        CHK(sH[tid], 2);
      }
      __syncthreads();
    }

    // ---- Phase O ----
    {
#pragma unroll
      for (int k = 0; k < 3; ++k) {
        const int c = tid + k * NTHREADS;
        if (c < 524) {
          float acc;
          if (c < 134) {
            acc = LD<F32>(br, c);
#pragma unroll 8
            for (int i = 0; i < DHH; ++i) acc += sH[i] * LD<F32>(Wr, i * 134 + c);
            sOr[c] = acc;
          } else {
            const int cw = c - 134;
            acc = LD<F32>(bw, cw);
#pragma unroll 8
            for (int i = 0; i < DHH; ++i) acc += sH[i] * LD<F32>(Ww, i * 390 + cw);
            sOw[cw] = acc;
          }
          CHK(acc, 3);
        }
      }
      __syncthreads();
      {
        float v = (tid < 128) ? sOr[tid] * sOr[tid]
                              : sOw[tid - 128] * sOw[tid - 128];
        v = waveSum(v);
        if (lane == 0) sP[wid] = v;
      }
      if (tid >= 128) sOw[134 + (tid - 128)] = sigmoid_(sOw[134 + (tid - 128)]);
      else            sOw[262 + tid]         = tanh_(sOw[262 + tid]);
      __syncthreads();
    }
    const float kn_r = sqrtf(sP[0] + sP[1]);
    const float kn_w = sqrtf(sP[2] + sP[3]);
    float beta_r, g_r, sr0, sr1, sr2, gam_r;
    float beta_w, g_w, sw0, sw1, sw2, gam_w;
    {
      beta_r = softplus_(sOr[128]); g_r = sigmoid_(sOr[129]);
      float a0 = sOr[130], a1 = sOr[131], a2 = sOr[132];
      float mx = fmaxf(a0, fmaxf(a1, a2));
      float e0 = __expf(a0 - mx), e1 = __expf(a1 - mx), e2 = __expf(a2 - mx);
      float es = e0 + e1 + e2;
      sr0 = e0 / es; sr1 = e1 / es; sr2 = e2 / es;
      gam_r = 1.0f + softplus_(sOr[133]);

      beta_w = softplus_(sOw[128]); g_w = sigmoid_(sOw[129]);
      float b0 = sOw[130], b1 = sOw[131], b2 = sOw[132];
      float mw = fmaxf(b0, fmaxf(b1, b2));
      float f0 = __expf(b0 - mw), f1 = __expf(b1 - mw), f2 = __expf(b2 - mw);
      float fs = f0 + f1 + f2;
      sw0 = f0 / fs; sw1 = f1 / fs; sw2 = f2 / fs;
      gam_w = 1.0f + softplus_(sOw[133]);
      if (tid == 0) {
        CHK(kn_r, 3); CHK(kn_w, 3); CHK(beta_r, 3); CHK(gam_r, 3);
        CHK(beta_w, 3); CHK(gam_w, 3);
      }
    }

    // ---- Phase A: dot_r, dot_w, ||mem_n|| ----
    {
      float krv[8], kwv[8];
#pragma unroll
      for (int j = 0; j < 8; ++j) { krv[j] = sOr[l * 8 + j]; kwv[j] = sOw[l * 8 + j]; }
#pragma unroll 4
      for (int it = 0; it < 32; ++it) {
        const int n = g + 16 * it;
        uint4 v = memv[n * 16 + l];
        union { uint4 v; unsigned short s[8]; } pk; pk.v = v;
        float m[8];
#pragma unroll
        for (int j = 0; j < 8; ++j) m[j] = us2f(pk.s[j]);
        float dr = 0.0f, dw = 0.0f, ss = 0.0f;
#pragma unroll
        for (int j = 0; j < 8; ++j) {
          dr += m[j] * krv[j];
          dw += m[j] * kwv[j];
          ss += m[j] * m[j];
        }
#pragma unroll
        for (int mm = 8; mm >= 1; mm >>= 1) {
          dr += __shfl_xor(dr, mm);
          dw += __shfl_xor(dw, mm);
          ss += __shfl_xor(ss, mm);
        }
        if (l == 0) {
          float nr = sqrtf(ss);
          sDotR[n] = dr; sDotW[n] = dw; sNrm[n] = nr;
          CHK(dr, 4); CHK(dw, 4); CHK(nr, 4);
        }
      }
      __syncthreads();
    }

    // ---- Attention ----
    attention_phase(tid, sDotR, sNrm, beta_r, g_r, sr0, sr1, sr2, gam_r, kn_r,
                    sWprev, sWg, sWr, sP + 4);
    CHK(sWr[tid], 5); CHK(sWr[tid + 256], 5);
    attention_phase(tid, sDotW, sNrm, beta_w, g_w, sw0, sw1, sw2, gam_w, kn_w,
                    sWr, sWg, sWprev, sP + 16);
    CHK(sWprev[tid], 6); CHK(sWprev[tid + 256], 6);

    // ---- Phase B: r = w_r·mem fused with mem update ----
    {
      float e8[8], a8[8], r8[8];
#pragma unroll
      for (int j = 0; j < 8; ++j) {
        e8[j] = sOw[134 + l * 8 + j];
        a8[j] = sOw[262 + l * 8 + j];
        r8[j] = 0.0f;
      }
#pragma unroll 2
      for (int it = 0; it < 32; ++it) {
        const int n = g + 16 * it;
        const float wrn = sWr[n];
        const float wwn = sWprev[n];
        union { uint4 v; unsigned short s[8]; } pk; pk.v = memv[n * 16 + l];
        float m[8];
#pragma unroll
        for (int j = 0; j < 8; ++j) m[j] = us2f(pk.s[j]);
#pragma unroll
        for (int j = 0; j < 8; ++j) {
          r8[j] = fmaf(wrn, m[j], r8[j]);
          float d = fmaf(-e8[j], m[j], a8[j]);
          m[j] = fmaf(wwn, d, m[j]);
        }
#pragma unroll
        for (int j = 0; j < 8; ++j) pk.s[j] = f2us(m[j]);
        memv[n * 16 + l] = pk.v;
      }
#pragma unroll
      for (int j = 0; j < 8; ++j) sRed[g * 128 + l * 8 + j] = r8[j];
      __syncthreads();
      if (tid < DHH) {
        float acc = 0.0f;
#pragma unroll
        for (int q = 0; q < 16; ++q) acc += sRed[q * 128 + tid];
        sR[tid] = acc;
        CHK(acc, 7);
      }
      __syncthreads();
    }

    // ---- Phase Y ----
    {
      const int j = tid & 127, p = tid >> 7;
      const float* src = p ? sR : sH;
      const int ib = p * 128;
      float acc = 0.0f;
#pragma unroll 8
      for (int i = 0; i < 128; ++i)
        acc += src[i] * LD<F32>(Wout, (ib + i) * DIN + j);
      sRed[tid] = acc;
      __syncthreads();
      if (tid < DIN) {
        float y = sRed[tid] + sRed[tid + 128] + LD<F32>(bout, tid);
        CHK(y, 8);
        ST<F32>(out, ((size_t)b * TSTEPS + t) * DIN + tid, y);
      }
      __syncthreads();
    }
  }

  // ---- diagnostic overwrite: absmax code = 1024*(1+first_bad_phase) [+16384 f32] ----
  __syncthreads();
  const unsigned bad = *sBadU;
  if (bad) {
    const int p = __ffs((int)bad) - 1;
    const float code = 1024.0f * (float)(1 + p) + (F32 ? 16384.0f : 0.0f);
    for (int i = tid; i < TSTEPS * DIN; i += NTHREADS)
      ST<F32>(out, (size_t)b * TSTEPS * DIN + i, code);
  }
}

extern "C" void kernel_launch(void* const* d_in, const int* in_sizes, int n_in,
                              void* d_out, int out_size, void* d_ws, size_t ws_size,
                              hipStream_t stream) {
  (void)in_sizes; (void)n_in; (void)out_size; (void)ws_size;
  const size_t smem = SMEM_FLOATS * sizeof(float);
  // Launch both dtype variants; each self-gates on the device-side sniff so
  // exactly one executes. Deterministic across launches (same input bits).
  ntm_kernel<false><<<dim3(BSZ), dim3(NTHREADS), smem, stream>>>(
      d_in[0], d_in[1], d_in[2], d_in[3], d_in[4], d_in[5], d_in[6],
      d_in[7], d_in[8], d_in[9], d_in[10], (unsigned short*)d_ws, d_out);
  ntm_kernel<true><<<dim3(BSZ), dim3(NTHREADS), smem, stream>>>(
      d_in[0], d_in[1], d_in[2], d_in[3], d_in[4], d_in[5], d_in[6],
      d_in[7], d_in[8], d_in[9], d_in[10], (unsigned short*)d_ws, d_out);
}

// Round 4
// 1299.509 us; speedup vs baseline: 1.9876x; 1.9876x over previous
//
#include <hip/hip_runtime.h>
#include <hip/hip_bf16.h>
#include <math.h>

#define NT 1024
#define BSZ 128
#define TSTEPS 32
#define DIN 128
#define DHH 128
#define NSLOT 512
#define EPSF 1e-8f

// LDS layout (bytes):
//   [0, 34304)        WrL  bf16[128*134]   persistent Wr
//   [34304, 134144)   WwL  bf16[128*390]   persistent Ww
//   [134144, 158816)  F    float[6168]     scratch
static constexpr size_t LDS_BYTES = 158816;

__device__ __forceinline__ float us2f(unsigned short u) {
  union { unsigned short s; __hip_bfloat16 h; } c; c.s = u; return __bfloat162float(c.h);
}
__device__ __forceinline__ unsigned short f2us(float f) {
  union { unsigned short s; __hip_bfloat16 h; } c; c.h = __float2bfloat16(f); return c.s;
}
__device__ __forceinline__ float sigmoid_(float x) { return 1.0f / (1.0f + __expf(-x)); }
__device__ __forceinline__ float softplus_(float x) {
  return fmaxf(x, 0.0f) + log1pf(__expf(-fabsf(x)));
}
__device__ __forceinline__ float tanh_(float x) {
  float e = __expf(-2.0f * fabsf(x));
  float t = (1.0f - e) / (1.0f + e);
  return copysignf(t, x);
}
__device__ __forceinline__ float waveSum(float v) {
#pragma unroll
  for (int m = 32; m >= 1; m >>= 1) v += __shfl_xor(v, m);
  return v;
}
__device__ __forceinline__ float waveMax(float v) {
#pragma unroll
  for (int m = 32; m >= 1; m >>= 1) v = fmaxf(v, __shfl_xor(v, m));
  return v;
}

// NTM attention head, 1024 threads, slot = tid (threads >=512 are passive but
// participate in all barriers / wave reductions with neutral values).
// sQ: 48-float region: [0..15] max partials, [16..31] expsum, [32..47] powsum.
__device__ __forceinline__ void attention_phase(
    int tid, const float* __restrict__ dot, const float* __restrict__ nrm,
    float beta, float g, float s0, float s1, float s2, float gam, float kn,
    const float* __restrict__ wprev, float* __restrict__ wg,
    float* __restrict__ wout_, float* __restrict__ sQ)
{
  const int lane = tid & 63, wid = tid >> 6;
  float sc = -1e30f;
  if (tid < NSLOT) sc = beta * dot[tid] / (nrm[tid] * kn + EPSF);
  float mx = waveMax(sc);
  if (lane == 0) sQ[wid] = mx;
  __syncthreads();
  float M = sQ[0];
#pragma unroll
  for (int q = 1; q < 16; ++q) M = fmaxf(M, sQ[q]);
  float e = (tid < NSLOT) ? __expf(sc - M) : 0.0f;
  float S = waveSum(e);
  if (lane == 0) sQ[16 + wid] = S;
  __syncthreads();
  float Ss = 0.0f;
#pragma unroll
  for (int q = 0; q < 16; ++q) Ss += sQ[16 + q];
  const float inv = 1.0f / Ss;
  if (tid < NSLOT) wg[tid] = g * (e * inv) + (1.0f - g) * wprev[tid];
  __syncthreads();
  float p = 0.0f;
  if (tid < NSLOT) {
    const float wt = s0 * wg[(tid + 1) & 511] + s1 * wg[tid] + s2 * wg[(tid - 1) & 511];
    p = powf(fmaxf(wt, 0.0f), gam);
  }
  float P = waveSum(p);
  if (lane == 0) sQ[32 + wid] = P;
  __syncthreads();
  float Ps = 0.0f;
#pragma unroll
  for (int q = 0; q < 16; ++q) Ps += sQ[32 + q];
  const float pinv = 1.0f / (Ps + EPSF);
  if (tid < NSLOT) wout_[tid] = p * pinv;
  __syncthreads();
}

// One block (1024 threads, 16 waves) per batch element; runs all 32 steps.
__global__ __launch_bounds__(NT, 4)
void ntm_kernel(const float* __restrict__ x,
                const float* __restrict__ Wxh,
                const float* __restrict__ Whh,
                const float* __restrict__ Wrh,
                const float* __restrict__ bh,
                const float* __restrict__ Wout,
                const float* __restrict__ bout,
                const float* __restrict__ Wr,
                const float* __restrict__ br,
                const float* __restrict__ Ww,
                const float* __restrict__ bw,
                unsigned short* __restrict__ memg,
                float* __restrict__ out)
{
  extern __shared__ char smem[];
  unsigned short* WrL = (unsigned short*)smem;             // 128x134 bf16
  unsigned short* WwL = (unsigned short*)(smem + 34304);   // 128x390 bf16
  float* F = (float*)(smem + 134144);

  const int b = blockIdx.x;
  const int tid = threadIdx.x;
  const int g = tid >> 4, l = tid & 15;   // 64 groups x 16 lanes (mem sweeps)
  const int lane = tid & 63, wid = tid >> 6;

  uint4* memv = (uint4*)(memg + (size_t)b * NSLOT * DHH);  // bf16 mem state

  float* sWprev = F + 0;      // 512  w_prev / becomes w_w
  float* sWr    = F + 512;    // 512  w_r
  float* sWg    = F + 1024;   // 512  attention scratch
  float* sDotR  = F + 1536;   // 512
  float* sDotW  = F + 2048;   // 512
  float* sNrm   = F + 2560;   // 512
  float* sRed   = F + 3072;   // 2048 reduction scratch
  float* sOr    = F + 5120;   // 144  (134 used)
  float* sOw    = F + 5264;   // 392  (390 used)
  float* sH     = F + 5656;   // 128
  float* sR     = F + 5784;   // 128
  float* sXt    = F + 5912;   // 128
  float* sP     = F + 6040;   // 128: [0..15] knorm, [16..63] attn1, [64..111] attn2

  // ---- one-time staging & state init ----
  for (int i = tid; i < DHH * 134; i += NT) WrL[i] = f2us(Wr[i]);
  for (int i = tid; i < DHH * 390; i += NT) WwL[i] = f2us(Ww[i]);
  {
    const unsigned short mb = f2us(1e-6f);
    const unsigned w32 = ((unsigned)mb << 16) | mb;
    const uint4 fv = make_uint4(w32, w32, w32, w32);
    for (int i = tid; i < NSLOT * DHH / 8; i += NT) memv[i] = fv;
  }
  for (int i = tid; i < NSLOT; i += NT) sWprev[i] = 1.0f / NSLOT;
  if (tid < DHH) { sH[tid] = 0.0f; sR[tid] = 0.0f; }
  __syncthreads();

  for (int t = 0; t < TSTEPS; ++t) {
    if (tid < DIN) sXt[tid] = x[((size_t)b * TSTEPS + t) * DIN + tid];
    __syncthreads();

    // ---- Phase H: h = tanh([x;h;r] @ [Wxh;Whh;Wrh] + bh) ----
    // thread = (col j, row-segment s of 48); 1024 partials -> 8-way combine
    {
      const int j = tid & 127, s = tid >> 7;
      const int i0 = s * 48;
      float acc = 0.0f;
#pragma unroll 4
      for (int q = 0; q < 48; ++q) {
        const int i = i0 + q;
        float v; const float* Wp;
        if (i < 128)      { v = sXt[i];       Wp = Wxh + i * DHH; }
        else if (i < 256) { v = sH[i - 128];  Wp = Whh + (i - 128) * DHH; }
        else              { v = sR[i - 256];  Wp = Wrh + (i - 256) * DHH; }
        acc += v * Wp[j];
      }
      sRed[tid] = acc;
      __syncthreads();
      if (tid < DHH) {
        float a2 = bh[tid];
#pragma unroll
        for (int q = 0; q < 8; ++q) a2 += sRed[tid + 128 * q];
        sH[tid] = tanh_(a2);
      }
      __syncthreads();
    }

    // ---- Phase O: o_r = h@Wr+br (134), o_w = h@Ww+bw (390), from LDS bf16 ----
    // 1048 partial-slots: slot<524 -> col c rows 0..63; else col c rows 64..127
    {
#pragma unroll
      for (int k = 0; k < 2; ++k) {
        const int slot = tid + k * NT;
        if (slot < 1048) {
          const int c  = (slot < 524) ? slot : slot - 524;
          const int r0 = (slot < 524) ? 0 : 64;
          float acc = 0.0f;
          if (c < 134) {
#pragma unroll 8
            for (int i = r0; i < r0 + 64; ++i) acc += sH[i] * us2f(WrL[i * 134 + c]);
          } else {
            const int cw = c - 134;
#pragma unroll 8
            for (int i = r0; i < r0 + 64; ++i) acc += sH[i] * us2f(WwL[i * 390 + cw]);
          }
          sRed[slot] = acc;
        }
      }
      __syncthreads();
      if (tid < 524) {
        const float v = sRed[tid] + sRed[524 + tid];
        if (tid < 134) sOr[tid] = v + br[tid];
        else           sOw[tid - 134] = v + bw[tid - 134];
      }
      __syncthreads();
      // k-norm partials (waves 0,1: |k_r|^2; waves 2,3: |k_w|^2) + e/a transforms
      {
        float v = 0.0f;
        if (tid < 128)      v = sOr[tid] * sOr[tid];
        else if (tid < 256) { const float z = sOw[tid - 128]; v = z * z; }
        v = waveSum(v);
        if (lane == 0) sP[wid] = v;
      }
      if (tid >= 256 && tid < 384)      { const int q = tid - 256; sOw[134 + q] = sigmoid_(sOw[134 + q]); }
      else if (tid >= 384 && tid < 512) { const int q = tid - 384; sOw[262 + q] = tanh_(sOw[262 + q]); }
      __syncthreads();
    }
    const float kn_r = sqrtf(sP[0] + sP[1]);
    const float kn_w = sqrtf(sP[2] + sP[3]);
    float beta_r, g_r, sr0, sr1, sr2, gam_r;
    float beta_w, g_w, sw0, sw1, sw2, gam_w;
    {
      beta_r = softplus_(sOr[128]); g_r = sigmoid_(sOr[129]);
      float a0 = sOr[130], a1 = sOr[131], a2 = sOr[132];
      float mx = fmaxf(a0, fmaxf(a1, a2));
      float e0 = __expf(a0 - mx), e1 = __expf(a1 - mx), e2 = __expf(a2 - mx);
      float es = e0 + e1 + e2;
      sr0 = e0 / es; sr1 = e1 / es; sr2 = e2 / es;
      gam_r = 1.0f + softplus_(sOr[133]);

      beta_w = softplus_(sOw[128]); g_w = sigmoid_(sOw[129]);
      float b0 = sOw[130], b1 = sOw[131], b2 = sOw[132];
      float mw = fmaxf(b0, fmaxf(b1, b2));
      float f0 = __expf(b0 - mw), f1 = __expf(b1 - mw), f2 = __expf(b2 - mw);
      float fs = f0 + f1 + f2;
      sw0 = f0 / fs; sw1 = f1 / fs; sw2 = f2 / fs;
      gam_w = 1.0f + softplus_(sOw[133]);
    }

    // ---- Phase A: dot_r[n], dot_w[n], ||mem_n|| — 64 groups, 8 slots each ----
    {
      float krv[8], kwv[8];
#pragma unroll
      for (int j = 0; j < 8; ++j) { krv[j] = sOr[l * 8 + j]; kwv[j] = sOw[l * 8 + j]; }
#pragma unroll 2
      for (int it = 0; it < 8; ++it) {
        const int n = g + 64 * it;
        union { uint4 v; unsigned short s[8]; } pk; pk.v = memv[n * 16 + l];
        float dr = 0.0f, dw = 0.0f, ss = 0.0f;
#pragma unroll
        for (int j = 0; j < 8; ++j) {
          const float m = us2f(pk.s[j]);
          dr += m * krv[j]; dw += m * kwv[j]; ss += m * m;
        }
#pragma unroll
        for (int mm = 8; mm >= 1; mm >>= 1) {
          dr += __shfl_xor(dr, mm);
          dw += __shfl_xor(dw, mm);
          ss += __shfl_xor(ss, mm);
        }
        if (l == 0) { sDotR[n] = dr; sDotW[n] = dw; sNrm[n] = sqrtf(ss); }
      }
      __syncthreads();
    }

    // ---- Attention: w_r (prev=w_prev) then w_w (prev=w_r; into sWprev) ----
    attention_phase(tid, sDotR, sNrm, beta_r, g_r, sr0, sr1, sr2, gam_r, kn_r,
                    sWprev, sWg, sWr, sP + 16);
    attention_phase(tid, sDotW, sNrm, beta_w, g_w, sw0, sw1, sw2, gam_w, kn_w,
                    sWr, sWg, sWprev, sP + 64);

    // ---- Phase B: r = w_r·mem (old) fused with mem update by w_w ----
    {
      float e8[8], a8[8], r8[8];
#pragma unroll
      for (int j = 0; j < 8; ++j) {
        e8[j] = sOw[134 + l * 8 + j];
        a8[j] = sOw[262 + l * 8 + j];
        r8[j] = 0.0f;
      }
#pragma unroll 2
      for (int it = 0; it < 8; ++it) {
        const int n = g + 64 * it;
        const float wrn = sWr[n];
        const float wwn = sWprev[n];   // holds w_w now
        union { uint4 v; unsigned short s[8]; } pk; pk.v = memv[n * 16 + l];
        float m[8];
#pragma unroll
        for (int j = 0; j < 8; ++j) m[j] = us2f(pk.s[j]);
#pragma unroll
        for (int j = 0; j < 8; ++j) {
          r8[j] = fmaf(wrn, m[j], r8[j]);
          const float d = fmaf(-e8[j], m[j], a8[j]);   // a - e*mem
          m[j] = fmaf(wwn, d, m[j]);                   // mem + w_w*(a - e*mem)
        }
#pragma unroll
        for (int j = 0; j < 8; ++j) pk.s[j] = f2us(m[j]);
        memv[n * 16 + l] = pk.v;
      }
      // reduce 4 groups within each wave (lanes l, l+16, l+32, l+48 share cols)
#pragma unroll
      for (int j = 0; j < 8; ++j) {
        r8[j] += __shfl_xor(r8[j], 16);
        r8[j] += __shfl_xor(r8[j], 32);
      }
      if (lane < 16) {
#pragma unroll
        for (int j = 0; j < 8; ++j) sRed[wid * 128 + lane * 8 + j] = r8[j];
      }
      __syncthreads();
      if (tid < DHH) {
        float acc = 0.0f;
#pragma unroll
        for (int q = 0; q < 16; ++q) acc += sRed[q * 128 + tid];
        sR[tid] = acc;
      }
      __syncthreads();
    }

    // ---- Phase Y: y = [h;r] @ Wout + bout ----
    {
      const int j = tid & 127, s = tid >> 7;
      const int r0 = s * 32;
      float acc = 0.0f;
#pragma unroll 4
      for (int q = 0; q < 32; ++q) {
        const int i = r0 + q;
        const float v = (i < 128) ? sH[i] : sR[i - 128];
        acc += v * Wout[i * DIN + j];
      }
      sRed[tid] = acc;
      __syncthreads();
      if (tid < DIN) {
        float y = bout[tid];
#pragma unroll
        for (int q = 0; q < 8; ++q) y += sRed[tid + 128 * q];
        out[((size_t)b * TSTEPS + t) * DIN + tid] = y;
      }
      __syncthreads();
    }
  }
}

extern "C" void kernel_launch(void* const* d_in, const int* in_sizes, int n_in,
                              void* d_out, int out_size, void* d_ws, size_t ws_size,
                              hipStream_t stream) {
  (void)in_sizes; (void)n_in; (void)out_size; (void)ws_size;
  hipFuncSetAttribute(reinterpret_cast<const void*>(ntm_kernel),
                      hipFuncAttributeMaxDynamicSharedMemorySize, (int)LDS_BYTES);
  ntm_kernel<<<dim3(BSZ), dim3(NT), LDS_BYTES, stream>>>(
      (const float*)d_in[0], (const float*)d_in[1], (const float*)d_in[2],
      (const float*)d_in[3], (const float*)d_in[4], (const float*)d_in[5],
      (const float*)d_in[6], (const float*)d_in[7], (const float*)d_in[8],
      (const float*)d_in[9], (const float*)d_in[10],
      (unsigned short*)d_ws, (float*)d_out);
}